// Round 1
// baseline (1546.231 us; speedup 1.0000x reference)
//
#include <hip/hip_runtime.h>

typedef float  f32x4 __attribute__((ext_vector_type(4)));
typedef short  s16x8 __attribute__((ext_vector_type(8)));
typedef unsigned short u16x8 __attribute__((ext_vector_type(8)));
typedef unsigned int   u32x4 __attribute__((ext_vector_type(4)));
typedef unsigned int   u32x2 __attribute__((ext_vector_type(2)));

constexpr int E = 8, H = 2048, IDIM = 4096, T = 8192;
constexpr float ALPHA = 1.702f, LIMIT = 7.0f;

__device__ __forceinline__ unsigned short f2bf(float f) {
    unsigned int u = __builtin_bit_cast(unsigned int, f);
    u += 0x7fffu + ((u >> 16) & 1u);           // round-to-nearest-even
    return (unsigned short)(u >> 16);
}

// pack two f32 -> packed bf16 (lo = a, hi = b)
__device__ __forceinline__ unsigned int pk_bf16(float a, float b) {
#if __has_builtin(__builtin_amdgcn_cvt_pk_bf16_f32)
    auto v = __builtin_amdgcn_cvt_pk_bf16_f32(a, b);
    return __builtin_bit_cast(unsigned int, v);
#else
    unsigned int ua = __builtin_bit_cast(unsigned int, a);
    unsigned int ub = __builtin_bit_cast(unsigned int, b);
    ua += 0x7fffu + ((ua >> 16) & 1u);
    ub += 0x7fffu + ((ub >> 16) & 1u);
    return __builtin_amdgcn_perm(ub, ua, 0x07060302);
#endif
}

__device__ __forceinline__ f32x4 mfma16(s16x8 a, s16x8 b, f32x4 c) {
    return __builtin_amdgcn_mfma_f32_16x16x32_bf16(a, b, c, 0, 0, 0);
}

// B swizzle: octet column n -> n ^ ((n>>2)&7)
__device__ __forceinline__ int bswz(int n) { return n ^ ((n >> 2) & 7); }

// ---------------------------------------------------------------------------
// Kernel 1: gate+up GEMM fused, pipelined double-buffer (issue-early /
// write-late). 512 threads, tile 128x128, BK=32, wave grid 2(M)x4(N).
// ---------------------------------------------------------------------------
__global__ __launch_bounds__(512, 2)
void gateup_kernel(const float* __restrict__ x, const int* __restrict__ offs,
                   const float* __restrict__ gate_w, const float* __restrict__ up_w,
                   const float* __restrict__ gate_b, const float* __restrict__ up_b,
                   unsigned short* __restrict__ act)
{
    __shared__ __align__(16) unsigned short As[2][4][128][8];
    __shared__ __align__(16) unsigned short Bg[2][4][128][8];
    __shared__ __align__(16) unsigned short Bu[2][4][128][8];

    const int tid  = threadIdx.x;
    const int row0 = blockIdx.y * 128;
    const int col0 = blockIdx.x * 128;

    int e = 0;
    while (e < E - 1 && row0 >= offs[e]) ++e;

    const float* gw = gate_w + (size_t)e * H * IDIM;
    const float* uw = up_w   + (size_t)e * H * IDIM;

    const int lane = tid & 63;
    const int wave = tid >> 6;          // 0..7
    const int wm   = (wave >> 2) * 64;  // 0 / 64
    const int wn   = (wave & 3) * 32;   // 0,32,64,96
    const int l15  = lane & 15;
    const int quad = lane >> 4;

    // A staging: one octet (8 floats of one row) per thread
    const int akb = tid & 3;            // k-octet 0..3
    const int am  = tid >> 2;           // row 0..127
    const float* asrc = x + (size_t)(row0 + am) * H + akb * 8;

    // B staging: 16 groups of 32 threads; each group = {gate|up} x k-octet x row-half
    const int n4   = (tid & 31) * 4;
    const int grp  = tid >> 5;          // 0..15
    const int bsel = grp >> 3;          // 0 = gate, 1 = up
    const int bkb  = (grp >> 1) & 3;    // k-octet
    const int brh  = grp & 1;           // row half within octet (4 rows)
    const float* bw = bsel ? uw : gw;
    const float* bsrc = bw + (size_t)(bkb * 8 + brh * 4) * IDIM + col0 + n4;

    const f32x4 fzero = {0.f, 0.f, 0.f, 0.f};
    f32x4 accg[4][2], accu[4][2];
#pragma unroll
    for (int i = 0; i < 4; ++i)
#pragma unroll
        for (int j = 0; j < 2; ++j) { accg[i][j] = fzero; accu[i][j] = fzero; }

    // in-flight staging registers (live across COMPUTE)
    f32x4 ra0, ra1, rb[4];

    auto LOAD = [&](int k0) {
        const float* s = asrc + k0;
        ra0 = *(const f32x4*)s;
        ra1 = *(const f32x4*)(s + 4);
        const float* b = bsrc + (size_t)k0 * IDIM;
#pragma unroll
        for (int r = 0; r < 4; ++r) rb[r] = *(const f32x4*)(b + (size_t)r * IDIM);
    };

    auto STORE = [&](int buf) {
        u32x4 o = { pk_bf16(ra0[0], ra0[1]), pk_bf16(ra0[2], ra0[3]),
                    pk_bf16(ra1[0], ra1[1]), pk_bf16(ra1[2], ra1[3]) };
        *(u32x4*)&As[buf][akb][am ^ (2 * akb)][0] = o;
        unsigned short* bb = bsel ? &Bu[buf][bkb][0][0] : &Bg[buf][bkb][0][0];
#pragma unroll
        for (int c = 0; c < 4; ++c) {
            u32x2 o2 = { pk_bf16(rb[0][c], rb[1][c]), pk_bf16(rb[2][c], rb[3][c]) };
            *(u32x2*)(bb + (size_t)bswz(n4 + c) * 8 + brh * 4) = o2;
        }
    };

    auto COMPUTE = [&](int buf) {
        s16x8 afr[4], bgf[2], buf2[2];
#pragma unroll
        for (int mi = 0; mi < 4; ++mi) {
            int m = wm + mi * 16 + l15;
            afr[mi] = *(const s16x8*)&As[buf][quad][m ^ (2 * quad)][0];
        }
#pragma unroll
        for (int ni = 0; ni < 2; ++ni) {
            int n = wn + ni * 16 + l15;
            bgf[ni]  = *(const s16x8*)&Bg[buf][quad][bswz(n)][0];
            buf2[ni] = *(const s16x8*)&Bu[buf][quad][bswz(n)][0];
        }
#pragma unroll
        for (int mi = 0; mi < 4; ++mi)
#pragma unroll
            for (int ni = 0; ni < 2; ++ni) {
                accg[mi][ni] = mfma16(afr[mi], bgf[ni],  accg[mi][ni]);
                accu[mi][ni] = mfma16(afr[mi], buf2[ni], accu[mi][ni]);
            }
    };

    // ---- pipelined main loop: 64 K-tiles, 1 barrier per tile
    LOAD(0); STORE(0); __syncthreads();
    int k = 32;
#pragma unroll 1
    for (int it = 0; it < 31; ++it) {
        LOAD(k); COMPUTE(0); STORE(1); __syncthreads(); k += 32;
        LOAD(k); COMPUTE(1); STORE(0); __syncthreads(); k += 32;
    }
    LOAD(k); COMPUTE(0); STORE(1); __syncthreads();
    COMPUTE(1);

    // ---- epilogue: bias + clamp + swiglu -> act bf16
#pragma unroll
    for (int ni = 0; ni < 2; ++ni) {
        int col = col0 + wn + ni * 16 + l15;
        float gb = gate_b[(size_t)e * IDIM + col];
        float ub = up_b[(size_t)e * IDIM + col];
#pragma unroll
        for (int mi = 0; mi < 4; ++mi) {
            int rowb = row0 + wm + mi * 16 + quad * 4;
#pragma unroll
            for (int r = 0; r < 4; ++r) {
                float g = accg[mi][ni][r] + gb;
                float u = accu[mi][ni][r] + ub;
                g = fminf(g, LIMIT);
                u = fminf(fmaxf(u, -LIMIT), LIMIT);
                float glu = g / (1.0f + __expf(-ALPHA * g));
                float av  = (u + 1.0f) * glu;
                act[(size_t)(rowb + r) * IDIM + col] = f2bf(av);
            }
        }
    }
}

// ---------------------------------------------------------------------------
// Kernel 2: down GEMM: act(bf16) @ down_w + down_b -> out fp32.
// 512 threads, tile 128x128, BK=64, pipelined double-buffer.
// ---------------------------------------------------------------------------
__global__ __launch_bounds__(512, 2)
void down_kernel(const unsigned short* __restrict__ act, const int* __restrict__ offs,
                 const float* __restrict__ down_w, const float* __restrict__ down_b,
                 float* __restrict__ out)
{
    __shared__ __align__(16) unsigned short As[2][8][128][8];
    __shared__ __align__(16) unsigned short Bs[2][8][128][8];

    const int tid  = threadIdx.x;
    const int row0 = blockIdx.y * 128;
    const int col0 = blockIdx.x * 128;

    int e = 0;
    while (e < E - 1 && row0 >= offs[e]) ++e;
    const float* dw = down_w + (size_t)e * IDIM * H;

    const int lane = tid & 63;
    const int wave = tid >> 6;
    const int wm   = (wave >> 2) * 64;
    const int wn   = (wave & 3) * 32;
    const int l15  = lane & 15;
    const int quad = lane >> 4;

    // A staging: two octets per thread (rows dm and dm+64, k-octet dkb)
    const int dkb = tid & 7;
    const int dm  = tid >> 3;   // 0..63
    const unsigned short* asrc0 = act + (size_t)(row0 + dm) * IDIM + dkb * 8;
    const unsigned short* asrc1 = act + (size_t)(row0 + dm + 64) * IDIM + dkb * 8;

    // B staging: 16 groups of 32 threads = k-octet(8) x row-half(2)
    const int n4  = (tid & 31) * 4;
    const int grp = tid >> 5;           // 0..15
    const int bkb = grp >> 1;           // 0..7
    const int brh = grp & 1;
    const float* bsrc = dw + (size_t)(bkb * 8 + brh * 4) * H + col0 + n4;

    const f32x4 fzero = {0.f, 0.f, 0.f, 0.f};
    f32x4 acc[4][2];
#pragma unroll
    for (int i = 0; i < 4; ++i)
#pragma unroll
        for (int j = 0; j < 2; ++j) acc[i][j] = fzero;

    u16x8 raA[2];
    f32x4 rb[4];

    auto LOAD = [&](int k0) {
        raA[0] = *(const u16x8*)(asrc0 + k0);
        raA[1] = *(const u16x8*)(asrc1 + k0);
        const float* b = bsrc + (size_t)k0 * H;
#pragma unroll
        for (int r = 0; r < 4; ++r) rb[r] = *(const f32x4*)(b + (size_t)r * H);
    };

    auto STORE = [&](int buf) {
        *(u16x8*)&As[buf][dkb][dm ^ dkb][0]        = raA[0];
        *(u16x8*)&As[buf][dkb][(dm + 64) ^ dkb][0] = raA[1];
#pragma unroll
        for (int c = 0; c < 4; ++c) {
            u32x2 o2 = { pk_bf16(rb[0][c], rb[1][c]), pk_bf16(rb[2][c], rb[3][c]) };
            *(u32x2*)(&Bs[buf][bkb][bswz(n4 + c)][0] + brh * 4) = o2;
        }
    };

    auto COMPUTE = [&](int buf) {
        s16x8 a0[4], a1[4], b0[2], b1[2];
#pragma unroll
        for (int mi = 0; mi < 4; ++mi) {
            int m = wm + mi * 16 + l15;
            a0[mi] = *(const s16x8*)&As[buf][quad    ][m ^ quad      ][0];
            a1[mi] = *(const s16x8*)&As[buf][quad + 4][m ^ (quad + 4)][0];
        }
#pragma unroll
        for (int ni = 0; ni < 2; ++ni) {
            int n = wn + ni * 16 + l15;
            b0[ni] = *(const s16x8*)&Bs[buf][quad    ][bswz(n)][0];
            b1[ni] = *(const s16x8*)&Bs[buf][quad + 4][bswz(n)][0];
        }
#pragma unroll
        for (int mi = 0; mi < 4; ++mi)
#pragma unroll
            for (int ni = 0; ni < 2; ++ni) {
                acc[mi][ni] = mfma16(a0[mi], b0[ni], acc[mi][ni]);
                acc[mi][ni] = mfma16(a1[mi], b1[ni], acc[mi][ni]);
            }
    };

    // ---- pipelined main loop: 64 K-tiles (BK=64), 1 barrier per tile
    LOAD(0); STORE(0); __syncthreads();
    int k = 64;
#pragma unroll 1
    for (int it = 0; it < 31; ++it) {
        LOAD(k); COMPUTE(0); STORE(1); __syncthreads(); k += 64;
        LOAD(k); COMPUTE(1); STORE(0); __syncthreads(); k += 64;
    }
    LOAD(k); COMPUTE(0); STORE(1); __syncthreads();
    COMPUTE(1);

    // ---- epilogue: + down_b, fp32 store
#pragma unroll
    for (int ni = 0; ni < 2; ++ni) {
        int col = col0 + wn + ni * 16 + l15;
        float db = down_b[(size_t)e * H + col];
#pragma unroll
        for (int mi = 0; mi < 4; ++mi) {
            int rowb = row0 + wm + mi * 16 + quad * 4;
#pragma unroll
            for (int r = 0; r < 4; ++r)
                out[(size_t)(rowb + r) * H + col] = acc[mi][ni][r] + db;
        }
    }
}

extern "C" void kernel_launch(void* const* d_in, const int* in_sizes, int n_in,
                              void* d_out, int out_size, void* d_ws, size_t ws_size,
                              hipStream_t stream) {
    const float* x      = (const float*)d_in[0];
    const int*   offs   = (const int*)d_in[1];
    const float* gate_w = (const float*)d_in[2];
    const float* up_w   = (const float*)d_in[3];
    const float* down_w = (const float*)d_in[4];
    const float* gate_b = (const float*)d_in[5];
    const float* up_b   = (const float*)d_in[6];
    const float* down_b = (const float*)d_in[7];
    float* out = (float*)d_out;
    unsigned short* act = (unsigned short*)d_ws;   // T x I bf16 = 64 MB

    dim3 blk(512);
    dim3 g1(IDIM / 128, T / 128);
    gateup_kernel<<<g1, blk, 0, stream>>>(x, offs, gate_w, up_w, gate_b, up_b, act);
    dim3 g2(H / 128, T / 128);
    down_kernel<<<g2, blk, 0, stream>>>(act, offs, down_w, down_b, out);
}